// Round 10
// baseline (190.492 us; speedup 1.0000x reference)
//
#include <hip/hip_runtime.h>

// SignalingModel: X_{t+1} = mml(W @ X_t + X_bias), 60 steps, W 0.24% sparse.
// R7 = R6 + degree-sorted node->thread permutation (divergence fix).
// Wave-max degree (~21) vs mean (10) inflated both DS and VALU pipes 2x;
// sorting nodes by in-degree makes lanes in a wave near-uniform.
// Permutation is computed with UNSTABLE LDS-atomic ranks: output is bitwise
// independent of perm (per-node edge loop order unchanged), so this stays
// deterministic for the harness.
// Carried lessons: LDS atomics in the hot loop ~16-25cy (R1/R3); per-step
// global structure re-reads = 20x transaction expansion (R4); edges in LDS +
// gather ownership + 1 barrier/step is the right dataflow (R5/R6).

#define NN 2048
#define STEPS 60
#define LEAKV 0.01f
#define EMAX 10240
#define TPB 1024
#define SPB 2
#define NB 64                                        // degree buckets
#define LDS_ENTRIES (EMAX * 8)                       // 81920 B
#define LDS_TOTAL (LDS_ENTRIES + SPB * 2 * NN * 4)   // 114688 B (112 KB)

__device__ __forceinline__ float mml_f(float x) {
  if (x < 0.0f)      return LEAKV * x;
  else if (x < 0.5f) return x;
  else               return 1.0f - 0.25f / x;
}

// --- build pipeline: CSR by target (edges sorted by (tgt,src)) ------------

__global__ __launch_bounds__(64) void count_row(const float* __restrict__ W,
                                                int* __restrict__ cnt) {
  const int n = blockIdx.x, lane = threadIdx.x;
  int c = 0;
  for (int c0 = 0; c0 < NN; c0 += 64) {
    float w = W[n * NN + c0 + lane];
    c += __popcll(__ballot(w != 0.0f));
  }
  if (lane == 0) cnt[n] = c;
}

__global__ __launch_bounds__(1024) void scan2048(const int* __restrict__ cnt,
                                                 int* __restrict__ base) {
  __shared__ int sb[2][NN];
  const int t = threadIdx.x;
  sb[0][t] = cnt[t];
  sb[0][t + 1024] = cnt[t + 1024];
  __syncthreads();
  int p = 0;
  for (int off = 1; off < NN; off <<= 1) {
    int i0 = t, i1 = t + 1024;
    sb[p ^ 1][i0] = sb[p][i0] + (i0 >= off ? sb[p][i0 - off] : 0);
    sb[p ^ 1][i1] = sb[p][i1] + (i1 >= off ? sb[p][i1 - off] : 0);
    __syncthreads();
    p ^= 1;
  }
  base[t] = sb[p][t] - cnt[t];
  base[t + 1024] = sb[p][t + 1024] - cnt[t + 1024];
  if (t == 1023) base[NN] = sb[p][NN - 1];   // total nnz
}

__global__ __launch_bounds__(64) void fill_edges(const float* __restrict__ W,
                                                 const int* __restrict__ base,
                                                 uint2* __restrict__ pg) {
  const int n = blockIdx.x, lane = threadIdx.x;
  const int b = base[n];
  int off = 0;
  for (int c0 = 0; c0 < NN; c0 += 64) {
    float w = W[n * NN + c0 + lane];
    unsigned long long m = __ballot(w != 0.0f);
    if (w != 0.0f) {
      int e = b + off + __popcll(m & ((1ull << lane) - 1ull));
      pg[e] = make_uint2(__float_as_uint(w), (unsigned)(c0 + lane));
    }
    off += __popcll(m);
  }
}

// degree counting-sort: perm[rank] = node, ranks ascending by degree.
// Unstable within a bucket (atomic order) -- output-invariant, see header.
__global__ __launch_bounds__(1024) void sortnodes(const int* __restrict__ cnt,
                                                  int* __restrict__ perm) {
  __shared__ int bases[NB];
  const int t = threadIdx.x;
  if (t < NB) bases[t] = 0;
  __syncthreads();
  int d0 = min(cnt[t], NB - 1);
  int d1 = min(cnt[t + 1024], NB - 1);
  atomicAdd(&bases[d0], 1);
  atomicAdd(&bases[d1], 1);
  __syncthreads();
  if (t == 0) {                       // serial 64-entry exclusive scan
    int acc = 0;
    for (int i = 0; i < NB; ++i) { int h = bases[i]; bases[i] = acc; acc += h; }
  }
  __syncthreads();
  perm[atomicAdd(&bases[d0], 1)] = t;
  perm[atomicAdd(&bases[d1], 1)] = t + 1024;
}

// --- simulation -----------------------------------------------------------
// one block = 2 samples; thread t owns nodes perm[2t], perm[2t+1] (degree-
// matched within a wave); state interleaved float2 {s0,s1}/node, ping-pong.
__global__ __launch_bounds__(TPB) void sim(const float* __restrict__ Xfull,
                                           const float* __restrict__ bias,
                                           const uint2* __restrict__ pg,
                                           const int* __restrict__ base,
                                           const int* __restrict__ perm,
                                           float* __restrict__ out) {
  extern __shared__ char smem[];
  uint2* E   = (uint2*)smem;                      // [EMAX] CSR entries
  float2* X0 = (float2*)(smem + LDS_ENTRIES);     // [NN] buffer 0 (s0,s1)
  float2* X1 = X0 + NN;                           // [NN] buffer 1

  const int t  = (int)threadIdx.x;
  const int s0 = (int)blockIdx.x * SPB;

  // one-time stage: coalesced global b64 -> linear LDS
#pragma unroll
  for (int i = 0; i < EMAX / TPB; ++i) {
    const int e = i * TPB + t;
    E[e] = pg[e];
  }

  const int nA = perm[2 * t];
  const int nB = perm[2 * t + 1];
  const int eA0 = base[nA], eA1 = base[nA + 1];
  const int eB0 = base[nB], eB1 = base[nB + 1];

  float2 xbA, xbB;   // component = sample
  {
    xbA = make_float2(Xfull[(size_t)s0 * NN + nA] + bias[nA],
                      Xfull[(size_t)(s0 + 1) * NN + nA] + bias[nA]);
    xbB = make_float2(Xfull[(size_t)s0 * NN + nB] + bias[nB],
                      Xfull[(size_t)(s0 + 1) * NN + nB] + bias[nB]);
  }
  // X1 = mml(W@0 + xb) = mml(xb)
  X0[nA] = make_float2(mml_f(xbA.x), mml_f(xbA.y));
  X0[nB] = make_float2(mml_f(xbB.x), mml_f(xbB.y));
  __syncthreads();

  float2* cur = X0;
  float2* nxt = X1;
  float2 yA = make_float2(0.f, 0.f), yB = yA;
  for (int it = 0; it < STEPS - 1; ++it) {   // produces X2..X60
    float2 aA = xbA;
    for (int e = eA0; e < eA1; ++e) {
      const uint2 en = E[e];
      const float w = __uint_as_float(en.x);
      const float2 v = cur[en.y];            // both samples, one b64
      aA.x += w * v.x;
      aA.y += w * v.y;
    }
    float2 aB = xbB;
    for (int e = eB0; e < eB1; ++e) {
      const uint2 en = E[e];
      const float w = __uint_as_float(en.x);
      const float2 v = cur[en.y];
      aB.x += w * v.x;
      aB.y += w * v.y;
    }
    yA = make_float2(mml_f(aA.x), mml_f(aA.y));
    yB = make_float2(mml_f(aB.x), mml_f(aB.y));
    nxt[nA] = yA;                            // scattered b64 stores
    nxt[nB] = yB;
    __syncthreads();                         // one barrier per step
    float2* tmp = cur; cur = nxt; nxt = tmp;
  }

  // final values still in registers; de-interleave (scattered 4B, once)
  out[(size_t)s0 * NN + nA]       = yA.x;
  out[(size_t)(s0 + 1) * NN + nA] = yA.y;
  out[(size_t)s0 * NN + nB]       = yB.x;
  out[(size_t)(s0 + 1) * NN + nB] = yB.y;
}

extern "C" void kernel_launch(void* const* d_in, const int* in_sizes, int n_in,
                              void* d_out, int out_size, void* d_ws, size_t ws_size,
                              hipStream_t stream) {
  const float* Xfull = (const float*)d_in[0];   // (B, N) f32
  const float* W     = (const float*)d_in[1];   // (N, N) f32
  const float* bias  = (const float*)d_in[2];   // (N, 1) f32
  float* out = (float*)d_out;

  // ws: pg[EMAX] uint2 (80KB) | cnt[NN] | base[NN+1] | perm[NN]
  char* ws = (char*)d_ws;
  uint2* pg = (uint2*)ws;
  int* cnt  = (int*)(ws + (size_t)EMAX * 8);
  int* base = (int*)(ws + (size_t)EMAX * 8 + (size_t)NN * 4);
  int* perm = (int*)(ws + (size_t)EMAX * 8 + (size_t)NN * 4 + (size_t)(NN + 1) * 4);

  const int B = in_sizes[0] / NN;   // 512

  hipFuncSetAttribute((const void*)sim,
                      hipFuncAttributeMaxDynamicSharedMemorySize, LDS_TOTAL);

  // zero edge tail (CSR never reads past nnz; keep LDS contents defined)
  hipMemsetAsync(pg, 0, (size_t)EMAX * 8, stream);
  count_row<<<NN, 64, 0, stream>>>(W, cnt);
  scan2048<<<1, 1024, 0, stream>>>(cnt, base);
  fill_edges<<<NN, 64, 0, stream>>>(W, base, pg);
  sortnodes<<<1, 1024, 0, stream>>>(cnt, perm);
  sim<<<B / SPB, TPB, LDS_TOTAL, stream>>>(Xfull, bias, pg, base, perm, out);
}

// Round 11
// 138.431 us; speedup vs baseline: 1.3761x; 1.3761x over previous
//
#include <hip/hip_runtime.h>

// SignalingModel: X_{t+1} = mml(W @ X_t + X_bias), 60 steps, W 0.24% sparse.
// R8 = R6 dataflow + degree-balanced ZIGZAG pairing + physical edge re-layout.
//  - thread t owns nA=perm[t] (asc degree), nB=perm[2047-t] (desc) -> within a
//    wave dA uniform AND dB uniform; pair sums flat across waves (max ~ deg_max).
//  - edges physically re-laid thread-contiguous (E2) -> lane-ordered entry
//    reads (R7's scattered-read conflict regression undone).
//  - per-node CSR edge order preserved -> output bitwise invariant to perm.
// Lessons: LDS atomics 16-25cy (R1/R3); per-step global re-reads 20x expansion
// (R4); barrier makes block time = slowest wave (R7); orderly entry reads
// matter (R7).

#define NN 2048
#define STEPS 60
#define LEAKV 0.01f
#define EMAX 10240
#define TPB 1024
#define SPB 2
#define NB 64                                        // degree buckets
#define LDS_ENTRIES (EMAX * 8)                       // 81920 B
#define LDS_TOTAL (LDS_ENTRIES + SPB * 2 * NN * 4)   // 114688 B (112 KB)

__device__ __forceinline__ float mml_f(float x) {
  if (x < 0.0f)      return LEAKV * x;
  else if (x < 0.5f) return x;
  else               return 1.0f - 0.25f / x;
}

// --- build pipeline -------------------------------------------------------

__global__ __launch_bounds__(64) void count_row(const float* __restrict__ W,
                                                int* __restrict__ cnt) {
  const int n = blockIdx.x, lane = threadIdx.x;
  int c = 0;
  for (int c0 = 0; c0 < NN; c0 += 64) {
    float w = W[n * NN + c0 + lane];
    c += __popcll(__ballot(w != 0.0f));
  }
  if (lane == 0) cnt[n] = c;
}

__global__ __launch_bounds__(1024) void scan2048(const int* __restrict__ cnt,
                                                 int* __restrict__ base) {
  __shared__ int sb[2][NN];
  const int t = threadIdx.x;
  sb[0][t] = cnt[t];
  sb[0][t + 1024] = cnt[t + 1024];
  __syncthreads();
  int p = 0;
  for (int off = 1; off < NN; off <<= 1) {
    int i0 = t, i1 = t + 1024;
    sb[p ^ 1][i0] = sb[p][i0] + (i0 >= off ? sb[p][i0 - off] : 0);
    sb[p ^ 1][i1] = sb[p][i1] + (i1 >= off ? sb[p][i1 - off] : 0);
    __syncthreads();
    p ^= 1;
  }
  base[t] = sb[p][t] - cnt[t];
  base[t + 1024] = sb[p][t + 1024] - cnt[t + 1024];
  if (t == 1023) base[NN] = sb[p][NN - 1];
}

__global__ __launch_bounds__(64) void fill_edges(const float* __restrict__ W,
                                                 const int* __restrict__ base,
                                                 uint2* __restrict__ pg) {
  const int n = blockIdx.x, lane = threadIdx.x;
  const int b = base[n];
  int off = 0;
  for (int c0 = 0; c0 < NN; c0 += 64) {
    float w = W[n * NN + c0 + lane];
    unsigned long long m = __ballot(w != 0.0f);
    if (w != 0.0f) {
      int e = b + off + __popcll(m & ((1ull << lane) - 1ull));
      pg[e] = make_uint2(__float_as_uint(w), (unsigned)(c0 + lane));
    }
    off += __popcll(m);
  }
}

// degree counting-sort: perm[rank]=node, ascending. Unstable within bucket
// (atomic order) -- output-invariant (per-node edge order preserved).
__global__ __launch_bounds__(1024) void sortnodes(const int* __restrict__ cnt,
                                                  int* __restrict__ perm) {
  __shared__ int bases[NB];
  const int t = threadIdx.x;
  if (t < NB) bases[t] = 0;
  __syncthreads();
  int d0 = min(cnt[t], NB - 1);
  int d1 = min(cnt[t + 1024], NB - 1);
  atomicAdd(&bases[d0], 1);
  atomicAdd(&bases[d1], 1);
  __syncthreads();
  if (t == 0) {
    int acc = 0;
    for (int i = 0; i < NB; ++i) { int h = bases[i]; bases[i] = acc; acc += h; }
  }
  __syncthreads();
  perm[atomicAdd(&bases[d0], 1)] = t;
  perm[atomicAdd(&bases[d1], 1)] = t + 1024;
}

// zigzag pair + thread-contiguous edge re-layout.
// thread t: nA=perm[t], nB=perm[2047-t]; E2[tb[t]..tb[t+1]) = A's CSR then B's.
__global__ __launch_bounds__(1024) void pair_layout(const int* __restrict__ cnt,
                                                    const int* __restrict__ base,
                                                    const uint2* __restrict__ pg,
                                                    const int* __restrict__ perm,
                                                    uint2* __restrict__ e2,
                                                    int* __restrict__ tb,
                                                    int* __restrict__ tmid,
                                                    int* __restrict__ pa,
                                                    int* __restrict__ pb) {
  __shared__ int sc[2][1024];
  const int t = threadIdx.x;
  const int nA = perm[t], nB = perm[2047 - t];
  const int dA = cnt[nA], dB = cnt[nB];
  sc[0][t] = dA + dB;
  __syncthreads();
  int p = 0;
  for (int off = 1; off < 1024; off <<= 1) {
    sc[p ^ 1][t] = sc[p][t] + (t >= off ? sc[p][t - off] : 0);
    __syncthreads();
    p ^= 1;
  }
  const int b = sc[p][t] - (dA + dB);     // exclusive
  tb[t] = b;
  tmid[t] = b + dA;
  pa[t] = nA;
  pb[t] = nB;
  if (t == 1023) tb[1024] = sc[p][t];
  const int bA = base[nA], bB = base[nB];
  for (int k = 0; k < dA; ++k) e2[b + k] = pg[bA + k];          // CSR order kept
  for (int k = 0; k < dB; ++k) e2[b + dA + k] = pg[bB + k];
}

// --- simulation -----------------------------------------------------------
// one block = 2 samples; state interleaved float2 {s0,s1}/node, ping-pong;
// thread t's edges contiguous in LDS at [tb[t], tb[t+1]).
__global__ __launch_bounds__(TPB) void sim(const float* __restrict__ Xfull,
                                           const float* __restrict__ bias,
                                           const uint2* __restrict__ e2,
                                           const int* __restrict__ tb,
                                           const int* __restrict__ tmid,
                                           const int* __restrict__ pa,
                                           const int* __restrict__ pb,
                                           float* __restrict__ out) {
  extern __shared__ char smem[];
  uint2* E   = (uint2*)smem;                      // [EMAX] thread-ordered
  float2* X0 = (float2*)(smem + LDS_ENTRIES);     // [NN] buffer 0 (s0,s1)
  float2* X1 = X0 + NN;                           // [NN] buffer 1

  const int t  = (int)threadIdx.x;
  const int s0 = (int)blockIdx.x * SPB;

#pragma unroll
  for (int i = 0; i < EMAX / TPB; ++i) {
    const int e = i * TPB + t;
    E[e] = e2[e];
  }

  const int nA = pa[t], nB = pb[t];
  const int eA0 = tb[t], eA1 = tmid[t], eB1 = tb[t + 1];

  float2 xbA = make_float2(Xfull[(size_t)s0 * NN + nA] + bias[nA],
                           Xfull[(size_t)(s0 + 1) * NN + nA] + bias[nA]);
  float2 xbB = make_float2(Xfull[(size_t)s0 * NN + nB] + bias[nB],
                           Xfull[(size_t)(s0 + 1) * NN + nB] + bias[nB]);
  // X1 = mml(W@0 + xb) = mml(xb)
  X0[nA] = make_float2(mml_f(xbA.x), mml_f(xbA.y));
  X0[nB] = make_float2(mml_f(xbB.x), mml_f(xbB.y));
  __syncthreads();

  float2* cur = X0;
  float2* nxt = X1;
  float2 yA = make_float2(0.f, 0.f), yB = yA;
  for (int it = 0; it < STEPS - 1; ++it) {   // produces X2..X60
    float2 aA = xbA;
    for (int e = eA0; e < eA1; ++e) {        // dA uniform within wave
      const uint2 en = E[e];
      const float w = __uint_as_float(en.x);
      const float2 v = cur[en.y];
      aA.x += w * v.x;
      aA.y += w * v.y;
    }
    float2 aB = xbB;
    for (int e = eA1; e < eB1; ++e) {        // dB uniform within wave
      const uint2 en = E[e];
      const float w = __uint_as_float(en.x);
      const float2 v = cur[en.y];
      aB.x += w * v.x;
      aB.y += w * v.y;
    }
    yA = make_float2(mml_f(aA.x), mml_f(aA.y));
    yB = make_float2(mml_f(aB.x), mml_f(aB.y));
    nxt[nA] = yA;
    nxt[nB] = yB;
    __syncthreads();                         // one barrier per step
    float2* tmp = cur; cur = nxt; nxt = tmp;
  }

  out[(size_t)s0 * NN + nA]       = yA.x;
  out[(size_t)(s0 + 1) * NN + nA] = yA.y;
  out[(size_t)s0 * NN + nB]       = yB.x;
  out[(size_t)(s0 + 1) * NN + nB] = yB.y;
}

extern "C" void kernel_launch(void* const* d_in, const int* in_sizes, int n_in,
                              void* d_out, int out_size, void* d_ws, size_t ws_size,
                              hipStream_t stream) {
  const float* Xfull = (const float*)d_in[0];   // (B, N) f32
  const float* W     = (const float*)d_in[1];   // (N, N) f32
  const float* bias  = (const float*)d_in[2];   // (N, 1) f32
  float* out = (float*)d_out;

  // ws: pg[EMAX]u2 | e2[EMAX]u2 | cnt[NN] | base[NN+1] | perm[NN] | tb[1025] | tmid[1024] | pa[1024] | pb[1024]
  char* ws = (char*)d_ws;
  uint2* pg = (uint2*)ws;                               ws += (size_t)EMAX * 8;
  uint2* e2 = (uint2*)ws;                               ws += (size_t)EMAX * 8;
  int* cnt  = (int*)ws;                                 ws += (size_t)NN * 4;
  int* base = (int*)ws;                                 ws += (size_t)(NN + 1) * 4;
  int* perm = (int*)ws;                                 ws += (size_t)NN * 4;
  int* tb   = (int*)ws;                                 ws += (size_t)1025 * 4;
  int* tmid = (int*)ws;                                 ws += (size_t)1024 * 4;
  int* pa   = (int*)ws;                                 ws += (size_t)1024 * 4;
  int* pb   = (int*)ws;

  const int B = in_sizes[0] / NN;   // 512

  hipFuncSetAttribute((const void*)sim,
                      hipFuncAttributeMaxDynamicSharedMemorySize, LDS_TOTAL);

  hipMemsetAsync(pg, 0, (size_t)EMAX * 16, stream);   // pg + e2 (tail defined)
  count_row<<<NN, 64, 0, stream>>>(W, cnt);
  scan2048<<<1, 1024, 0, stream>>>(cnt, base);
  fill_edges<<<NN, 64, 0, stream>>>(W, base, pg);
  sortnodes<<<1, 1024, 0, stream>>>(cnt, perm);
  pair_layout<<<1, 1024, 0, stream>>>(cnt, base, pg, perm, e2, tb, tmid, pa, pb);
  sim<<<B / SPB, TPB, LDS_TOTAL, stream>>>(Xfull, bias, e2, tb, tmid, pa, pb, out);
}

// Round 12
// 113.643 us; speedup vs baseline: 1.6762x; 1.2181x over previous
//
#include <hip/hip_runtime.h>

// SignalingModel: X_{t+1} = mml(W @ X_t + X_bias), 60 steps, W 0.24% sparse.
// R9 = R8 build + REGISTER-RESIDENT edges in sim.
//  - fixed EPT=12 slots/thread, fully unrolled, compile-time indices ->
//    compiler keeps wA[12], wB[12], boff[12] in VGPRs (rule #20 satisfied).
//  - A/B routing precomputed into two weight regs (one is 0) -> no per-edge
//    select, no entry reads in the hot loop: 12 x {ds_read_b64, 4 fma}.
//  - pairs with >12 edges: short spill loop from global e2 (L1-hot, ~100
//    edges total thanks to zigzag balance).
//  - LDS = 32 KB state only (static); entry staging eliminated.
// Lessons: LDS atomics 16-25cy (R1/R3); per-step global re-reads of the FULL
// structure = 20x expansion (R4); step-invariant entry re-reads from LDS were
// ~half the DS ops (R8); barrier makes block time = slowest wave (R7).

#define NN 2048
#define STEPS 60
#define LEAKV 0.01f
#define EMAX 10240
#define TPB 1024
#define SPB 2
#define NB 64
#define EPT 12            // register slots per thread (pair-sum p99 ~ 13)

__device__ __forceinline__ float mml_f(float x) {
  if (x < 0.0f)      return LEAKV * x;
  else if (x < 0.5f) return x;
  else               return 1.0f - 0.25f / x;
}

// --- build pipeline (unchanged from R8) -----------------------------------

__global__ __launch_bounds__(64) void count_row(const float* __restrict__ W,
                                                int* __restrict__ cnt) {
  const int n = blockIdx.x, lane = threadIdx.x;
  int c = 0;
  for (int c0 = 0; c0 < NN; c0 += 64) {
    float w = W[n * NN + c0 + lane];
    c += __popcll(__ballot(w != 0.0f));
  }
  if (lane == 0) cnt[n] = c;
}

__global__ __launch_bounds__(1024) void scan2048(const int* __restrict__ cnt,
                                                 int* __restrict__ base) {
  __shared__ int sb[2][NN];
  const int t = threadIdx.x;
  sb[0][t] = cnt[t];
  sb[0][t + 1024] = cnt[t + 1024];
  __syncthreads();
  int p = 0;
  for (int off = 1; off < NN; off <<= 1) {
    int i0 = t, i1 = t + 1024;
    sb[p ^ 1][i0] = sb[p][i0] + (i0 >= off ? sb[p][i0 - off] : 0);
    sb[p ^ 1][i1] = sb[p][i1] + (i1 >= off ? sb[p][i1 - off] : 0);
    __syncthreads();
    p ^= 1;
  }
  base[t] = sb[p][t] - cnt[t];
  base[t + 1024] = sb[p][t + 1024] - cnt[t + 1024];
  if (t == 1023) base[NN] = sb[p][NN - 1];
}

__global__ __launch_bounds__(64) void fill_edges(const float* __restrict__ W,
                                                 const int* __restrict__ base,
                                                 uint2* __restrict__ pg) {
  const int n = blockIdx.x, lane = threadIdx.x;
  const int b = base[n];
  int off = 0;
  for (int c0 = 0; c0 < NN; c0 += 64) {
    float w = W[n * NN + c0 + lane];
    unsigned long long m = __ballot(w != 0.0f);
    if (w != 0.0f) {
      int e = b + off + __popcll(m & ((1ull << lane) - 1ull));
      pg[e] = make_uint2(__float_as_uint(w), (unsigned)(c0 + lane));
    }
    off += __popcll(m);
  }
}

// degree counting-sort: perm[rank]=node, ascending. Unstable within bucket --
// output-invariant (per-node edge order preserved regardless of owner thread).
__global__ __launch_bounds__(1024) void sortnodes(const int* __restrict__ cnt,
                                                  int* __restrict__ perm) {
  __shared__ int bases[NB];
  const int t = threadIdx.x;
  if (t < NB) bases[t] = 0;
  __syncthreads();
  int d0 = min(cnt[t], NB - 1);
  int d1 = min(cnt[t + 1024], NB - 1);
  atomicAdd(&bases[d0], 1);
  atomicAdd(&bases[d1], 1);
  __syncthreads();
  if (t == 0) {
    int acc = 0;
    for (int i = 0; i < NB; ++i) { int h = bases[i]; bases[i] = acc; acc += h; }
  }
  __syncthreads();
  perm[atomicAdd(&bases[d0], 1)] = t;
  perm[atomicAdd(&bases[d1], 1)] = t + 1024;
}

// zigzag pair + thread-contiguous edge re-layout (CSR order preserved).
__global__ __launch_bounds__(1024) void pair_layout(const int* __restrict__ cnt,
                                                    const int* __restrict__ base,
                                                    const uint2* __restrict__ pg,
                                                    const int* __restrict__ perm,
                                                    uint2* __restrict__ e2,
                                                    int* __restrict__ tb,
                                                    int* __restrict__ tmid,
                                                    int* __restrict__ pa,
                                                    int* __restrict__ pb) {
  __shared__ int sc[2][1024];
  const int t = threadIdx.x;
  const int nA = perm[t], nB = perm[2047 - t];
  const int dA = cnt[nA], dB = cnt[nB];
  sc[0][t] = dA + dB;
  __syncthreads();
  int p = 0;
  for (int off = 1; off < 1024; off <<= 1) {
    sc[p ^ 1][t] = sc[p][t] + (t >= off ? sc[p][t - off] : 0);
    __syncthreads();
    p ^= 1;
  }
  const int b = sc[p][t] - (dA + dB);
  tb[t] = b;
  tmid[t] = b + dA;
  pa[t] = nA;
  pb[t] = nB;
  if (t == 1023) tb[1024] = sc[p][t];
  const int bA = base[nA], bB = base[nB];
  for (int k = 0; k < dA; ++k) e2[b + k] = pg[bA + k];
  for (int k = 0; k < dB; ++k) e2[b + dA + k] = pg[bB + k];
}

// --- simulation -----------------------------------------------------------
// one block = 2 samples; state interleaved float2 {s0,s1}/node, ping-pong in
// 32 KB static LDS; 12 edges/thread in REGISTERS; spill (>12) from global.
__global__ __launch_bounds__(TPB) void sim(const float* __restrict__ Xfull,
                                           const float* __restrict__ bias,
                                           const uint2* __restrict__ e2,
                                           const int* __restrict__ tb,
                                           const int* __restrict__ tmid,
                                           const int* __restrict__ pa,
                                           const int* __restrict__ pb,
                                           float* __restrict__ out) {
  __shared__ float2 X[2][NN];                     // 32 KB
  const int t  = (int)threadIdx.x;
  const int s0 = (int)blockIdx.x * SPB;

  const int nA = pa[t], nB = pb[t];
  const int eA0 = tb[t], eA1 = tmid[t], eB1 = tb[t + 1];

  // hoist edges into registers: static unroll, compile-time indices only.
  float wA[EPT], wB[EPT];
  int boff[EPT];                                  // byte offset into X row
#pragma unroll
  for (int k = 0; k < EPT; ++k) {
    const int idx = eA0 + k;
    const bool val = idx < eB1;
    const uint2 en = e2[val ? idx : eA0];         // clamped, masked below
    const float wv = val ? __uint_as_float(en.x) : 0.0f;
    const bool isA = idx < eA1;
    wA[k] = isA ? wv : 0.0f;
    wB[k] = isA ? 0.0f : wv;
    boff[k] = val ? (int)(en.y * 8u) : 0;
  }

  float2 xbA = make_float2(Xfull[(size_t)s0 * NN + nA] + bias[nA],
                           Xfull[(size_t)(s0 + 1) * NN + nA] + bias[nA]);
  float2 xbB = make_float2(Xfull[(size_t)s0 * NN + nB] + bias[nB],
                           Xfull[(size_t)(s0 + 1) * NN + nB] + bias[nB]);
  // X1 = mml(W@0 + xb) = mml(xb)
  X[0][nA] = make_float2(mml_f(xbA.x), mml_f(xbA.y));
  X[0][nB] = make_float2(mml_f(xbB.x), mml_f(xbB.y));
  __syncthreads();

  int cur = 0;
  float2 yA = make_float2(0.f, 0.f), yB = yA;
  for (int it = 0; it < STEPS - 1; ++it) {        // produces X2..X60
    const char* __restrict__ Xc = (const char*)&X[cur][0];
    float2 aA = xbA, aB = xbB;
#pragma unroll
    for (int k = 0; k < EPT; ++k) {               // zero divergence
      const float2 v = *(const float2*)(Xc + boff[k]);
      aA.x += wA[k] * v.x;
      aA.y += wA[k] * v.y;
      aB.x += wB[k] * v.x;
      aB.y += wB[k] * v.y;
    }
    for (int e = eA0 + EPT; e < eB1; ++e) {       // rare spill lanes
      const uint2 en = e2[e];                     // L1-hot global
      const float w = __uint_as_float(en.x);
      const float2 v = *(const float2*)(Xc + en.y * 8u);
      if (e < eA1) { aA.x += w * v.x; aA.y += w * v.y; }
      else         { aB.x += w * v.x; aB.y += w * v.y; }
    }
    yA = make_float2(mml_f(aA.x), mml_f(aA.y));
    yB = make_float2(mml_f(aB.x), mml_f(aB.y));
    X[cur ^ 1][nA] = yA;
    X[cur ^ 1][nB] = yB;
    __syncthreads();                              // one barrier per step
    cur ^= 1;
  }

  out[(size_t)s0 * NN + nA]       = yA.x;
  out[(size_t)(s0 + 1) * NN + nA] = yA.y;
  out[(size_t)s0 * NN + nB]       = yB.x;
  out[(size_t)(s0 + 1) * NN + nB] = yB.y;
}

extern "C" void kernel_launch(void* const* d_in, const int* in_sizes, int n_in,
                              void* d_out, int out_size, void* d_ws, size_t ws_size,
                              hipStream_t stream) {
  const float* Xfull = (const float*)d_in[0];   // (B, N) f32
  const float* W     = (const float*)d_in[1];   // (N, N) f32
  const float* bias  = (const float*)d_in[2];   // (N, 1) f32
  float* out = (float*)d_out;

  // ws: pg[EMAX]u2 | e2[EMAX]u2 | cnt[NN] | base[NN+1] | perm[NN] | tb[1025] | tmid[1024] | pa[1024] | pb[1024]
  char* ws = (char*)d_ws;
  uint2* pg = (uint2*)ws;                               ws += (size_t)EMAX * 8;
  uint2* e2 = (uint2*)ws;                               ws += (size_t)EMAX * 8;
  int* cnt  = (int*)ws;                                 ws += (size_t)NN * 4;
  int* base = (int*)ws;                                 ws += (size_t)(NN + 1) * 4;
  int* perm = (int*)ws;                                 ws += (size_t)NN * 4;
  int* tb   = (int*)ws;                                 ws += (size_t)1025 * 4;
  int* tmid = (int*)ws;                                 ws += (size_t)1024 * 4;
  int* pa   = (int*)ws;                                 ws += (size_t)1024 * 4;
  int* pb   = (int*)ws;

  const int B = in_sizes[0] / NN;   // 512

  hipMemsetAsync(pg, 0, (size_t)EMAX * 16, stream);   // pg + e2 tails defined
  count_row<<<NN, 64, 0, stream>>>(W, cnt);
  scan2048<<<1, 1024, 0, stream>>>(cnt, base);
  fill_edges<<<NN, 64, 0, stream>>>(W, base, pg);
  sortnodes<<<1, 1024, 0, stream>>>(cnt, perm);
  pair_layout<<<1, 1024, 0, stream>>>(cnt, base, pg, perm, e2, tb, tmid, pa, pb);
  sim<<<B / SPB, TPB, 0, stream>>>(Xfull, bias, e2, tb, tmid, pa, pb, out);
}